// Round 10
// baseline (265.029 us; speedup 1.0000x reference)
//
#include <hip/hip_runtime.h>
#include <math.h>

#define LEVELS 16
#define FEAT 2
#define NLDSL 12            // levels 0..11 eligible for LDS corner-dedup
#define LDS_CAP 2560        // float2 slots (20 KiB) for the corner cache
#define CNT_CAP 768         // per-level corner cap (beyond this VMEM is cheaper)

// Ns[l] = python round(16 * 1.5^l)  (banker's rounding; exact in fp32)
__constant__ float c_Ns[LEVELS] = {
    16.f, 24.f, 36.f, 54.f, 81.f, 122.f, 182.f, 273.f,
    410.f, 615.f, 923.f, 1384.f, 2076.f, 3114.f, 4671.f, 7006.f
};

#define P1 2654435761u
#define P2 805459861u

template <bool POW2_TABLE>
__device__ __forceinline__ unsigned hash2d(unsigned ux, unsigned uy, unsigned sd,
                                           unsigned tsize, unsigned tmask) {
    const unsigned h = (ux * P1) ^ (uy * P2) ^ sd;
    return POW2_TABLE ? (h & tmask) : (h % tsize);
}

// ---------------- fast path: one block == 256 consecutive pixels of ONE row
// (requires W % 256 == 0). Levels 0..NLDSL-1: block-cooperative corner cache
// in LDS (x-cells are one contiguous range, y-cells are 2 values -> corners
// enumerable without per-thread hashing). Levels NLDSL..15: per-thread random
// gathers, issued BEFORE the loader so their latency hides under it.
template <bool POW2_TABLE>
__global__ __launch_bounds__(256) void hashenc_lds_kernel(
    const float* __restrict__ x0v,
    const float* __restrict__ y0v,
    const float2* __restrict__ tables,
    const unsigned int* __restrict__ seeds,
    const int* __restrict__ tile_ptr,
    float* __restrict__ out,
    int N,              // H*W
    int bpr,            // blocks per row = W/256
    unsigned int tsize,
    unsigned int tmask)
{
    __shared__ float2 ltab[LDS_CAP];

    const int tid = threadIdx.x;
    const int b = blockIdx.y;
    const int row = blockIdx.x / bpr;                  // block-uniform
    const int j0 = (blockIdx.x - row * bpr) * 256;
    const int j = j0 + tid;

    // scales: bit-exact vs reference f32 Ns/tile (pow2 tile -> exact rcp)
    const int tile = *tile_ptr;
    const float tilef = (float)tile;
    float sc[LEVELS];
    if ((tile & (tile - 1)) == 0) {
        const float it = 1.0f / tilef;
#pragma unroll
        for (int l = 0; l < LEVELS; ++l) sc[l] = c_Ns[l] * it;
    } else {
#pragma unroll
        for (int l = 0; l < LEVELS; ++l) sc[l] = c_Ns[l] / tilef;
    }

    const float xb = x0v[b];
    const float px = (float)j + xb;
    const float py = (float)row + y0v[b];              // block-uniform
    const float pxl = (float)j0 + xb;                  // leftmost pixel
    const float pxr = (float)(j0 + 255) + xb;          // rightmost pixel

    // ---- fine levels: compute indices + issue all gathers NOW ----
    float ffx[LEVELS - NLDSL], ffy[LEVELS - NLDSL];
    float2 fr[LEVELS - NLDSL][4];
#pragma unroll
    for (int k = 0; k < LEVELS - NLDSL; ++k) {
        const int l = NLDSL + k;
        const float s = sc[l];
        const float xsf = px * s, ysf = py * s;
        const float fx0 = floorf(xsf), fy0 = floorf(ysf);
        ffx[k] = xsf - fx0;
        ffy[k] = ysf - fy0;
        const unsigned ux = (unsigned)(int)fx0;
        const unsigned uy = (unsigned)(int)fy0;
        const unsigned sd = seeds[l];
        fr[k][0] = tables[hash2d<POW2_TABLE>(ux,      uy,      sd, tsize, tmask)];
        fr[k][1] = tables[hash2d<POW2_TABLE>(ux + 1u, uy,      sd, tsize, tmask)];
        fr[k][2] = tables[hash2d<POW2_TABLE>(ux,      uy + 1u, sd, tsize, tmask)];
        fr[k][3] = tables[hash2d<POW2_TABLE>(ux + 1u, uy + 1u, sd, tsize, tmask)];
    }
    __builtin_amdgcn_sched_barrier(0);  // keep fine gathers issued before loader

    // ---- loader: block-cooperative corner cache for levels 0..NLDSL-1 ----
    // Geometry recomputed identically here and in the consumer (uniform math,
    // no arrays -> no VGPR blowup, no scratch).
    {
        int run = 0;
#pragma unroll
        for (int l = 0; l < NLDSL; ++l) {
            const float s = sc[l];
            const int x0i = (int)floorf(pxl * s);
            const int x1i = (int)floorf(pxr * s);
            const int iy0 = (int)floorf(py * s);       // uniform (one row)
            const int xlen = x1i - x0i + 2;            // corners x0i..x1i+1
            const int cnt = 2 * xlen;                  // two y rows
            if (cnt <= CNT_CAP && run + cnt <= LDS_CAP) {
                const unsigned sd = seeds[l];
                for (int t = tid; t < cnt; t += 256) {
                    const int dy = (t >= xlen) ? 1 : 0;
                    const int xo = t - dy * xlen;
                    const unsigned ux = (unsigned)(x0i + xo);
                    const unsigned uy = (unsigned)(iy0 + dy);
                    ltab[run + t] = tables[hash2d<POW2_TABLE>(ux, uy, sd, tsize, tmask)];
                }
                run += cnt;
            }
        }
    }
    __syncthreads();

    float* outb = out + (size_t)b * (size_t)(LEVELS * FEAT) * (size_t)N
                      + (size_t)(row * (bpr * 256) + j0 + tid);

    // ---- fine math first (frees fr registers early) ----
#pragma unroll
    for (int k = 0; k < LEVELS - NLDSL; ++k) {
        const int l = NLDSL + k;
        const float fx = ffx[k], fy = ffy[k];
        const float omx = 1.0f - fx, omy = 1.0f - fy;
        const float w00 = omx * omy, w10 = fx * omy;
        const float w01 = omx * fy, w11 = fx * fy;
        const float2 f00 = fr[k][0], f10 = fr[k][1];
        const float2 f01 = fr[k][2], f11 = fr[k][3];
        const float e0 = w00 * f00.x + w10 * f10.x + w01 * f01.x + w11 * f11.x;
        const float e1 = w00 * f00.y + w10 * f10.y + w01 * f01.y + w11 * f11.y;
        __builtin_nontemporal_store(e0, outb + (size_t)(2 * l) * (size_t)N);
        __builtin_nontemporal_store(e1, outb + (size_t)(2 * l + 1) * (size_t)N);
    }

    // ---- LDS-cached levels ----
    {
        int run = 0;
#pragma unroll
        for (int l = 0; l < NLDSL; ++l) {
            const float s = sc[l];
            const int x0i = (int)floorf(pxl * s);
            const int x1i = (int)floorf(pxr * s);
            const int xlen = x1i - x0i + 2;
            const int cnt = 2 * xlen;
            const bool inlds = (cnt <= CNT_CAP && run + cnt <= LDS_CAP);

            const float xsf = px * s, ysf = py * s;
            const float fx0 = floorf(xsf), fy0 = floorf(ysf);
            const float fx = xsf - fx0, fy = ysf - fy0;

            float2 f00, f10, f01, f11;
            if (inlds) {
                // iy0 == loader's iy0 (identical uniform expr) -> dy == 0
                const int a = run + ((int)fx0 - x0i);
                f00 = ltab[a];
                f10 = ltab[a + 1];
                f01 = ltab[a + xlen];
                f11 = ltab[a + xlen + 1];
                run += cnt;
            } else {
                const unsigned ux = (unsigned)(int)fx0;
                const unsigned uy = (unsigned)(int)fy0;
                const unsigned sd = seeds[l];
                f00 = tables[hash2d<POW2_TABLE>(ux,      uy,      sd, tsize, tmask)];
                f10 = tables[hash2d<POW2_TABLE>(ux + 1u, uy,      sd, tsize, tmask)];
                f01 = tables[hash2d<POW2_TABLE>(ux,      uy + 1u, sd, tsize, tmask)];
                f11 = tables[hash2d<POW2_TABLE>(ux + 1u, uy + 1u, sd, tsize, tmask)];
            }

            const float omx = 1.0f - fx, omy = 1.0f - fy;
            const float w00 = omx * omy, w10 = fx * omy;
            const float w01 = omx * fy, w11 = fx * fy;
            const float e0 = w00 * f00.x + w10 * f10.x + w01 * f01.x + w11 * f11.x;
            const float e1 = w00 * f00.y + w10 * f10.y + w01 * f01.y + w11 * f11.y;
            __builtin_nontemporal_store(e0, outb + (size_t)(2 * l) * (size_t)N);
            __builtin_nontemporal_store(e1, outb + (size_t)(2 * l + 1) * (size_t)N);
        }
    }
}

// ---------------- fallback: round-4 kernel (general W) ----------------
template <bool POW2_TABLE, bool POW2_W>
__global__ __launch_bounds__(256) void hashenc_kernel(
    const float* __restrict__ x0,
    const float* __restrict__ y0,
    const float2* __restrict__ tables,
    const unsigned int* __restrict__ seeds,
    const int* __restrict__ tile_ptr,
    float* __restrict__ out,
    int N, int W, int wshift,
    unsigned int tsize, unsigned int tmask)
{
    const int pix = blockIdx.x * blockDim.x + threadIdx.x;
    if (pix >= N) return;
    const int b = blockIdx.y;

    int i, j;
    if (POW2_W) { i = pix >> wshift; j = pix & (W - 1); }
    else        { i = pix / W;       j = pix - i * W;   }

    const int tile = *tile_ptr;
    const float tilef = (float)tile;
    float sc[LEVELS];
    if ((tile & (tile - 1)) == 0) {
        const float it = 1.0f / tilef;
#pragma unroll
        for (int l = 0; l < LEVELS; ++l) sc[l] = c_Ns[l] * it;
    } else {
#pragma unroll
        for (int l = 0; l < LEVELS; ++l) sc[l] = c_Ns[l] / tilef;
    }

    const float px = (float)j + x0[b];
    const float py = (float)i + y0[b];
    float* outb = out + (size_t)b * (size_t)(LEVELS * FEAT) * (size_t)N + pix;

#pragma unroll
    for (int l = 0; l < LEVELS; ++l) {
        const float s = sc[l];
        const float xs = px * s, ys = py * s;
        const float fx0 = floorf(xs), fy0 = floorf(ys);
        const float fx = xs - fx0, fy = ys - fy0;
        const unsigned ux = (unsigned)(int)fx0;
        const unsigned uy = (unsigned)(int)fy0;
        const unsigned sd = seeds[l];
        const float2 f00 = tables[hash2d<POW2_TABLE>(ux,      uy,      sd, tsize, tmask)];
        const float2 f10 = tables[hash2d<POW2_TABLE>(ux + 1u, uy,      sd, tsize, tmask)];
        const float2 f01 = tables[hash2d<POW2_TABLE>(ux,      uy + 1u, sd, tsize, tmask)];
        const float2 f11 = tables[hash2d<POW2_TABLE>(ux + 1u, uy + 1u, sd, tsize, tmask)];
        const float omx = 1.0f - fx, omy = 1.0f - fy;
        const float w00 = omx * omy, w10 = fx * omy;
        const float w01 = omx * fy, w11 = fx * fy;
        const float e0 = w00 * f00.x + w10 * f10.x + w01 * f01.x + w11 * f11.x;
        const float e1 = w00 * f00.y + w10 * f10.y + w01 * f01.y + w11 * f11.y;
        __builtin_nontemporal_store(e0, outb + (size_t)(2 * l) * (size_t)N);
        __builtin_nontemporal_store(e1, outb + (size_t)(2 * l + 1) * (size_t)N);
    }
}

extern "C" void kernel_launch(void* const* d_in, const int* in_sizes, int n_in,
                              void* d_out, int out_size, void* d_ws, size_t ws_size,
                              hipStream_t stream) {
    const float* x0 = (const float*)d_in[0];
    const float* y0 = (const float*)d_in[1];
    const float2* tables = (const float2*)d_in[2];
    const unsigned int* seeds = (const unsigned int*)d_in[3];
    // d_in[4] = memorized_crop_size (geometry derived from out_size)
    const int* tile_ptr = (const int*)d_in[5];

    const int Bn = in_sizes[0];
    const unsigned int tsize = (unsigned int)(in_sizes[2] / FEAT);
    const int N = out_size / (Bn * LEVELS * FEAT);       // H*W
    const int W = (int)(sqrt((double)N) + 0.5);          // H == W in reference
    float* out = (float*)d_out;
    const bool pow2_table = (tsize & (tsize - 1)) == 0;

    if (W >= 256 && (W % 256) == 0) {
        const int bpr = W / 256;
        dim3 grid(N / 256, Bn);
        if (pow2_table)
            hashenc_lds_kernel<true><<<grid, 256, 0, stream>>>(
                x0, y0, tables, seeds, tile_ptr, out, N, bpr, tsize, tsize - 1u);
        else
            hashenc_lds_kernel<false><<<grid, 256, 0, stream>>>(
                x0, y0, tables, seeds, tile_ptr, out, N, bpr, tsize, 0u);
        return;
    }

    int wshift = 0;
    while ((1 << wshift) < W) ++wshift;
    dim3 grid((N + 255) / 256, Bn);
    const bool pow2_w = (W & (W - 1)) == 0;
    if (pow2_table && pow2_w)
        hashenc_kernel<true, true><<<grid, 256, 0, stream>>>(
            x0, y0, tables, seeds, tile_ptr, out, N, W, wshift, tsize, tsize - 1u);
    else if (pow2_table)
        hashenc_kernel<true, false><<<grid, 256, 0, stream>>>(
            x0, y0, tables, seeds, tile_ptr, out, N, W, wshift, tsize, tsize - 1u);
    else if (pow2_w)
        hashenc_kernel<false, true><<<grid, 256, 0, stream>>>(
            x0, y0, tables, seeds, tile_ptr, out, N, W, wshift, tsize, 0u);
    else
        hashenc_kernel<false, false><<<grid, 256, 0, stream>>>(
            x0, y0, tables, seeds, tile_ptr, out, N, W, wshift, tsize, 0u);
}